// Round 4
// baseline (131.274 us; speedup 1.0000x reference)
//
#include <hip/hip_runtime.h>
#include <math.h>

#define Bq 4
#define Nq 128
#define Cq 256
#define HFq 23
#define WFq 30
#define PHq 7
#define PWq 7
#define HIDq 256
#define OUTq 5
#define Fq (Cq*PHq*PWq)      // 12544
#define Mq (Bq*Nq)           // 512
#define HWq (HFq*WFq)        // 690
#define SCALEq (1.0f/32.0f)
#define NEGq (-1e30f)
#define KHq 5                // HF//PH + 2
#define KWq 6                // WF//PW + 2
#define SPLITK 14
#define KCH (Fq/SPLITK)      // 896
#define BKq 64
#define BMq 128
#define KSTEPS (KCH/BKq)     // 14

typedef float f32x4 __attribute__((ext_vector_type(4)));
typedef __bf16 bf16x8 __attribute__((ext_vector_type(8)));
typedef unsigned short u16x8 __attribute__((ext_vector_type(8)));

__device__ __forceinline__ unsigned short f2b(float f) {
    unsigned int u = __float_as_uint(f);
    unsigned int r = (u + 0x7FFFu + ((u >> 16) & 1u)) >> 16;
    return (unsigned short)r;
}

// K1: fused prep. blockIdx.x ranges:
//   [0,704)   : transpose features (B,C,HF,WF) f32 -> (B, HF*WF, C) bf16
//   [704,960) : W1 f32 (HID, c*49+cell) -> bf16 permuted (HID, cell*256+c)
//   [960,968) : zero h (atomicAdd target for split-K GEMM1)
__global__ __launch_bounds__(256) void k_prep(const float* __restrict__ feat,
                                              unsigned short* __restrict__ ft,
                                              const float* __restrict__ W1,
                                              unsigned short* __restrict__ w1p,
                                              float* __restrict__ h) {
    __shared__ __align__(16) unsigned short smem[Fq];   // 25088 B overlay
    int bid = blockIdx.x;
    int tid = threadIdx.x;
    if (bid < 704) {
        // --- transpose tile, f32 -> bf16 ---
        float (*t)[33] = (float (*)[33])smem;           // 32*33*4 = 4224 B
        int bb  = bid / 176;
        int rem = bid % 176;
        int x0 = (rem % 22) * 32;      // HW dim
        int c0 = (rem / 22) * 32;      // C dim
        int tx = tid & 31, ty = tid >> 5;
        const float* src = feat + (size_t)bb * Cq * HWq;
        unsigned short* dst = ft + (size_t)bb * HWq * Cq;
#pragma unroll
        for (int i = 0; i < 4; ++i) {
            int c = c0 + ty + i * 8;
            int x = x0 + tx;
            if (x < HWq) t[ty + i * 8][tx] = src[(size_t)c * HWq + x];  // t[c_loc][x_loc]
        }
        __syncthreads();
        int u = tid & 15, xl = tid >> 4;
#pragma unroll
        for (int i = 0; i < 2; ++i) {
            int xloc = xl + i * 16;
            int x = x0 + xloc;
            if (x < HWq) {
                ushort2 o;
                o.x = f2b(t[u * 2][xloc]);
                o.y = f2b(t[u * 2 + 1][xloc]);
                *(ushort2*)(dst + (size_t)x * Cq + c0 + u * 2) = o;
            }
        }
    } else if (bid < 960) {
        // --- W1 permute + bf16 convert ---
        int j = bid - 704;
        const float4* src = (const float4*)(W1 + (size_t)j * Fq);
        for (int i = tid; i < Fq / 4; i += 256) {
            float4 v = src[i];
            ushort4 o;
            o.x = f2b(v.x); o.y = f2b(v.y); o.z = f2b(v.z); o.w = f2b(v.w);
            ((ushort4*)smem)[i] = o;
        }
        __syncthreads();
        uint4* dst = (uint4*)(w1p + (size_t)j * Fq);
        for (int i = tid; i < Fq / 8; i += 256) {
            int base = i * 8;
            int cell = base >> 8;       // 8 consecutive c share one cell
            int c0v = base & 255;
            unsigned short tmp[8];
#pragma unroll
            for (int u2 = 0; u2 < 8; ++u2) tmp[u2] = smem[(c0v + u2) * 49 + cell];
            dst[i] = *(const uint4*)tmp;
        }
    } else {
        // --- zero h: 512 KB, 8 blocks x 256 threads x 16 float4 ---
        f32x4* h4 = (f32x4*)h;
        int base = (bid - 960) * 4096;
        f32x4 z = {0.f, 0.f, 0.f, 0.f};
#pragma unroll
        for (int u2 = 0; u2 < 16; ++u2) h4[base + u2 * 256 + tid] = z;
    }
}

// K2: ROI max pool over bf16 ft. 16 waves per proposal (grid (Mq,4)),
// each wave covers 3-4 cells. Lane split: cl = lane&31 -> 8 channels;
// half = lane>>5 -> w-positions. Combine via shfl_xor(32).
__global__ __launch_bounds__(256) void k_pool(const unsigned short* __restrict__ ft,
                                              const float* __restrict__ props,
                                              unsigned short* __restrict__ pooled) {
    int wave = threadIdx.x >> 6;
    int lane = threadIdx.x & 63;
    int half = lane >> 5;
    int cl = lane & 31;
    int g = blockIdx.y * 4 + wave;   // cell group 0..15
    int m = blockIdx.x;              // proposal
    int b = m >> 7;
    const float* pr = props + (size_t)m * 5;
    float b0 = pr[0] * SCALEq, b1v = pr[1] * SCALEq;
    float b2v = pr[2] * SCALEq, b3v = pr[3] * SCALEq;
    int x1 = min(max((int)floorf(b0), 0), WFq - 1);
    int y1 = min(max((int)floorf(b1v), 0), HFq - 1);
    int rw = min(max((int)ceilf(b2v) - x1, 1), WFq);
    int rh = min(max((int)ceilf(b3v) - y1, 1), HFq);
    const unsigned short* ftb = ft + (size_t)b * HWq * Cq + cl * 8;
    unsigned short* pm = pooled + (size_t)m * Fq + cl * 8;

    for (int cell = g; cell < PHq * PWq; cell += 16) {
        int ph = cell / 7;
        int pw = cell - ph * 7;
        int hs = y1 + (ph * rh) / PHq;
        int he = min(y1 + ((ph + 1) * rh + PHq - 1) / PHq, HFq);
        int ws = x1 + (pw * rw) / PWq;
        int we = min(x1 + ((pw + 1) * rw + PWq - 1) / PWq, WFq);
        float acc[8];
#pragma unroll
        for (int u = 0; u < 8; ++u) acc[u] = NEGq;
#pragma unroll
        for (int kh = 0; kh < KHq; ++kh) {
            if (hs + kh < he) {                      // wave-uniform
                const unsigned short* rowp = ftb + (size_t)((hs + kh) * WFq) * Cq;
#pragma unroll
                for (int kw2 = 0; kw2 < 3; ++kw2) {
                    int w = ws + kw2 * 2 + half;
                    if (w < we) {                    // half-wave divergent only
                        u16x8 v = *(const u16x8*)(rowp + (size_t)w * Cq);
#pragma unroll
                        for (int u = 0; u < 8; ++u)
                            acc[u] = fmaxf(acc[u], __uint_as_float((unsigned)v[u] << 16));
                    }
                }
            }
        }
#pragma unroll
        for (int u = 0; u < 8; ++u) acc[u] = fmaxf(acc[u], __shfl_xor(acc[u], 32));
        if (half == 0) {
            u16x8 o;
#pragma unroll
            for (int u = 0; u < 8; ++u) o[u] = f2b(acc[u]);
            *(u16x8*)(pm + (size_t)cell * Cq) = o;
        }
    }
}

// K3: GEMM1 with MFMA bf16. BM=128, BN=64, BK=64, double-buffered LDS with
// XOR-swizzled 16B chunks (chunk' = chunk ^ (row&7)). 2-step reg lookahead.
// Split-K partials accumulated into h via atomicAdd (h pre-zeroed).
__global__ __launch_bounds__(256) void k_gemm1(const unsigned short* __restrict__ pooled,
                                               const unsigned short* __restrict__ w1p,
                                               float* __restrict__ h) {
    __shared__ __align__(16) unsigned short As[2][BMq * BKq];  // 2 x 16 KB
    __shared__ __align__(16) unsigned short Bs[2][64 * BKq];   // 2 x 8 KB
    int m0 = blockIdx.x * BMq;
    int j0 = blockIdx.y * 64;
    int kz = blockIdx.z;
    int tid = threadIdx.x;
    // A staging: row rA = tid>>1 (0..127), chunks [cA, cA+4)
    int rA = tid >> 1, cA = (tid & 1) * 4;
    const uint4* ap = (const uint4*)(pooled + (size_t)(m0 + rA) * Fq + (size_t)kz * KCH) + cA;
    // B staging: row rB = tid>>2 (0..63), chunks qq and qq^4
    int rB = tid >> 2, qq = tid & 3;
    const uint4* bp = (const uint4*)(w1p + (size_t)(j0 + rB) * Fq + (size_t)kz * KCH) + qq;
    int lane = tid & 63, wv = tid >> 6;
    int q = lane >> 4, mr = lane & 15;
    f32x4 acc00 = {0.f,0.f,0.f,0.f}, acc01 = {0.f,0.f,0.f,0.f};
    f32x4 acc02 = {0.f,0.f,0.f,0.f}, acc03 = {0.f,0.f,0.f,0.f};
    f32x4 acc10 = {0.f,0.f,0.f,0.f}, acc11 = {0.f,0.f,0.f,0.f};
    f32x4 acc12 = {0.f,0.f,0.f,0.f}, acc13 = {0.f,0.f,0.f,0.f};
    int swA = rA & 7, swB = rB & 7;
    int stB1 = rB * 8 + (qq ^ swB);
    int stB2 = rB * 8 + ((qq ^ 4) ^ swB);

    uint4 av[4], bv0, bv1;
#pragma unroll
    for (int u = 0; u < 4; ++u) av[u] = ap[u];
    bv0 = bp[0]; bv1 = bp[4];
    {
        uint4* aw = (uint4*)As[0];
        uint4* bw = (uint4*)Bs[0];
#pragma unroll
        for (int u = 0; u < 4; ++u) aw[rA * 8 + ((cA + u) ^ swA)] = av[u];
        bw[stB1] = bv0; bw[stB2] = bv1;
    }
#pragma unroll
    for (int u = 0; u < 4; ++u) av[u] = ap[8 + u];
    bv0 = bp[8]; bv1 = bp[12];

    for (int s = 0; s < KSTEPS; ++s) {
        __syncthreads();
        int cur = s & 1;
        if (s + 1 < KSTEPS) {
            uint4* aw = (uint4*)As[cur ^ 1];
            uint4* bw = (uint4*)Bs[cur ^ 1];
#pragma unroll
            for (int u = 0; u < 4; ++u) aw[rA * 8 + ((cA + u) ^ swA)] = av[u];
            bw[stB1] = bv0; bw[stB2] = bv1;
            if (s + 2 < KSTEPS) {
#pragma unroll
                for (int u = 0; u < 4; ++u) av[u] = ap[(s + 2) * 8 + u];
                bv0 = bp[(s + 2) * 8]; bv1 = bp[(s + 2) * 8 + 4];
            }
        }
        const bf16x8* Ab = (const bf16x8*)As[cur];
        const bf16x8* Bb = (const bf16x8*)Bs[cur];
#pragma unroll
        for (int kk = 0; kk < 2; ++kk) {
            int ck = (kk * 4 + q) ^ (mr & 7);
            bf16x8 a0 = Ab[(wv * 32 + mr) * 8 + ck];
            bf16x8 a1 = Ab[(wv * 32 + 16 + mr) * 8 + ck];
            bf16x8 bb0 = Bb[(0  + mr) * 8 + ck];
            bf16x8 bb1 = Bb[(16 + mr) * 8 + ck];
            bf16x8 bb2 = Bb[(32 + mr) * 8 + ck];
            bf16x8 bb3 = Bb[(48 + mr) * 8 + ck];
            acc00 = __builtin_amdgcn_mfma_f32_16x16x32_bf16(a0, bb0, acc00, 0, 0, 0);
            acc01 = __builtin_amdgcn_mfma_f32_16x16x32_bf16(a0, bb1, acc01, 0, 0, 0);
            acc02 = __builtin_amdgcn_mfma_f32_16x16x32_bf16(a0, bb2, acc02, 0, 0, 0);
            acc03 = __builtin_amdgcn_mfma_f32_16x16x32_bf16(a0, bb3, acc03, 0, 0, 0);
            acc10 = __builtin_amdgcn_mfma_f32_16x16x32_bf16(a1, bb0, acc10, 0, 0, 0);
            acc11 = __builtin_amdgcn_mfma_f32_16x16x32_bf16(a1, bb1, acc11, 0, 0, 0);
            acc12 = __builtin_amdgcn_mfma_f32_16x16x32_bf16(a1, bb2, acc12, 0, 0, 0);
            acc13 = __builtin_amdgcn_mfma_f32_16x16x32_bf16(a1, bb3, acc13, 0, 0, 0);
        }
    }
    int jj = j0 + mr;
#pragma unroll
    for (int r2 = 0; r2 < 4; ++r2) {
        float* row0 = h + (size_t)(m0 + wv * 32 + q * 4 + r2) * HIDq + jj;
        atomicAdd(row0 + 0,  acc00[r2]);
        atomicAdd(row0 + 16, acc01[r2]);
        atomicAdd(row0 + 32, acc02[r2]);
        atomicAdd(row0 + 48, acc03[r2]);
        float* row1 = h + (size_t)(m0 + wv * 32 + 16 + q * 4 + r2) * HIDq + jj;
        atomicAdd(row1 + 0,  acc10[r2]);
        atomicAdd(row1 + 16, acc11[r2]);
        atomicAdd(row1 + 32, acc12[r2]);
        atomicAdd(row1 + 48, acc13[r2]);
    }
}

// K4: tail — 8 proposals per block. bias + relu on split-K sum,
// GEMM2 (512 x 5 x 256) + epilogue.
__global__ __launch_bounds__(256) void k_tail(const float* __restrict__ h,
                                              const float* __restrict__ b1,
                                              const float* __restrict__ W2,
                                              const float* __restrict__ b2,
                                              const float* __restrict__ props,
                                              float* __restrict__ out) {
    __shared__ float red[8][OUTq][4];
    int j = threadIdx.x;
    int lane = j & 63, wid = j >> 6;
    int m0 = blockIdx.x * 8;
    float b1v = b1[j];
    float hv[8];
#pragma unroll
    for (int i = 0; i < 8; ++i)
        hv[i] = fmaxf(h[(size_t)(m0 + i) * HIDq + j] + b1v, 0.f);
    float w2v[OUTq];
#pragma unroll
    for (int o = 0; o < OUTq; ++o) w2v[o] = W2[(size_t)o * HIDq + j];
#pragma unroll
    for (int i = 0; i < 8; ++i) {
#pragma unroll
        for (int o = 0; o < OUTq; ++o) {
            float v = hv[i] * w2v[o];
            v += __shfl_xor(v, 1);
            v += __shfl_xor(v, 2);
            v += __shfl_xor(v, 4);
            v += __shfl_xor(v, 8);
            v += __shfl_xor(v, 16);
            v += __shfl_xor(v, 32);
            if (lane == 0) red[i][o][wid] = v;
        }
    }
    __syncthreads();
    if (j < 8 * OUTq) {
        int i = j / OUTq, o = j - i * OUTq;
        int m = m0 + i;
        float s = red[i][o][0] + red[i][o][1] + red[i][o][2] + red[i][o][3] + b2[o];
        float pv = props[(size_t)m * 5 + o];
        float r;
        if (o < 4) r = pv + s;
        else r = 1.f / (1.f + expf(-(pv + s)));
        out[(size_t)m * 5 + o] = r;
    }
}

extern "C" void kernel_launch(void* const* d_in, const int* in_sizes, int n_in,
                              void* d_out, int out_size, void* d_ws, size_t ws_size,
                              hipStream_t stream) {
    const float* feat  = (const float*)d_in[0];   // (4,256,23,30)
    const float* props = (const float*)d_in[1];   // (4,128,5)
    const float* W1    = (const float*)d_in[2];   // (256,12544)
    const float* b1    = (const float*)d_in[3];   // (256,)
    const float* W2    = (const float*)d_in[4];   // (5,256)
    const float* b2    = (const float*)d_in[5];   // (5,)
    float* out = (float*)d_out;

    char* ws = (char*)d_ws;
    unsigned short* ft     = (unsigned short*)(ws);              // 1,413,120 B (bf16)
    unsigned short* w1p    = (unsigned short*)(ws + 1413120);    // 6,422,528 B
    unsigned short* pooled = (unsigned short*)(ws + 7835648);    // 12,845,056 B
    float* h               = (float*)(ws + 20680704);            // 524,288 B -> 21,204,992 total

    k_prep<<<968, 256, 0, stream>>>(feat, ft, W1, w1p, h);
    k_pool<<<dim3(Mq, 4), 256, 0, stream>>>(ft, props, pooled);
    k_gemm1<<<dim3(Mq / BMq, HIDq / 64, SPLITK), 256, 0, stream>>>(pooled, w1p, h);
    k_tail<<<Mq / 8, 256, 0, stream>>>(h, b1, W2, b2, props, out);
}

// Round 5
// 115.780 us; speedup vs baseline: 1.1338x; 1.1338x over previous
//
#include <hip/hip_runtime.h>
#include <math.h>

#define Bq 4
#define Nq 128
#define Cq 256
#define HFq 23
#define WFq 30
#define PHq 7
#define PWq 7
#define HIDq 256
#define OUTq 5
#define Fq (Cq*PHq*PWq)      // 12544
#define Mq (Bq*Nq)           // 512
#define HWq (HFq*WFq)        // 690
#define SCALEq (1.0f/32.0f)
#define NEGq (-1e30f)
#define KHq 5                // HF//PH + 2
#define KWq 6                // WF//PW + 2
#define SPLITK 14
#define KCH (Fq/SPLITK)      // 896
#define BKq 64
#define KSTEPS (KCH/BKq)     // 14

typedef float f32x4 __attribute__((ext_vector_type(4)));
typedef __bf16 bf16x8 __attribute__((ext_vector_type(8)));
typedef unsigned short u16x8 __attribute__((ext_vector_type(8)));

__device__ __forceinline__ unsigned short f2b(float f) {
    unsigned int u = __float_as_uint(f);
    unsigned int r = (u + 0x7FFFu + ((u >> 16) & 1u)) >> 16;
    return (unsigned short)r;
}

// K1: fused prep. blockIdx.x ranges:
//   [0,704)   : transpose features (B,C,HF,WF) f32 -> (B, HF*WF, C) bf16
//   [704,960) : W1 f32 (HID, c*49+cell) -> bf16 permuted (HID, cell*256+c)
//   [960,968) : zero h (atomicAdd target for split-K GEMM1)
__global__ __launch_bounds__(256) void k_prep(const float* __restrict__ feat,
                                              unsigned short* __restrict__ ft,
                                              const float* __restrict__ W1,
                                              unsigned short* __restrict__ w1p,
                                              float* __restrict__ h) {
    __shared__ __align__(16) unsigned short smem[Fq];   // 25088 B overlay
    int bid = blockIdx.x;
    int tid = threadIdx.x;
    if (bid < 704) {
        // --- transpose tile, f32 -> bf16 ---
        float (*t)[33] = (float (*)[33])smem;           // 32*33*4 = 4224 B
        int bb  = bid / 176;
        int rem = bid % 176;
        int x0 = (rem % 22) * 32;      // HW dim
        int c0 = (rem / 22) * 32;      // C dim
        int tx = tid & 31, ty = tid >> 5;
        const float* src = feat + (size_t)bb * Cq * HWq;
        unsigned short* dst = ft + (size_t)bb * HWq * Cq;
#pragma unroll
        for (int i = 0; i < 4; ++i) {
            int c = c0 + ty + i * 8;
            int x = x0 + tx;
            if (x < HWq) t[ty + i * 8][tx] = src[(size_t)c * HWq + x];  // t[c_loc][x_loc]
        }
        __syncthreads();
        int u = tid & 15, xl = tid >> 4;
#pragma unroll
        for (int i = 0; i < 2; ++i) {
            int xloc = xl + i * 16;
            int x = x0 + xloc;
            if (x < HWq) {
                ushort2 o;
                o.x = f2b(t[u * 2][xloc]);
                o.y = f2b(t[u * 2 + 1][xloc]);
                *(ushort2*)(dst + (size_t)x * Cq + c0 + u * 2) = o;
            }
        }
    } else if (bid < 960) {
        // --- W1 permute + bf16 convert ---
        int j = bid - 704;
        const float4* src = (const float4*)(W1 + (size_t)j * Fq);
        for (int i = tid; i < Fq / 4; i += 256) {
            float4 v = src[i];
            ushort4 o;
            o.x = f2b(v.x); o.y = f2b(v.y); o.z = f2b(v.z); o.w = f2b(v.w);
            ((ushort4*)smem)[i] = o;
        }
        __syncthreads();
        uint4* dst = (uint4*)(w1p + (size_t)j * Fq);
        for (int i = tid; i < Fq / 8; i += 256) {
            int base = i * 8;
            int cell = base >> 8;       // 8 consecutive c share one cell
            int c0v = base & 255;
            unsigned short tmp[8];
#pragma unroll
            for (int u2 = 0; u2 < 8; ++u2) tmp[u2] = smem[(c0v + u2) * 49 + cell];
            dst[i] = *(const uint4*)tmp;
        }
    } else {
        // --- zero h: 512 KB, 8 blocks x 256 threads x 16 float4 ---
        f32x4* h4 = (f32x4*)h;
        int base = (bid - 960) * 4096;
        f32x4 z = {0.f, 0.f, 0.f, 0.f};
#pragma unroll
        for (int u2 = 0; u2 < 16; ++u2) h4[base + u2 * 256 + tid] = z;
    }
}

// K2: ROI max pool over bf16 ft. 16 waves per proposal (grid (Mq,4)),
// each wave covers 3-4 cells. Lane split: cl = lane&31 -> 8 channels;
// half = lane>>5 -> w-positions. Combine via shfl_xor(32).
__global__ __launch_bounds__(256) void k_pool(const unsigned short* __restrict__ ft,
                                              const float* __restrict__ props,
                                              unsigned short* __restrict__ pooled) {
    int wave = threadIdx.x >> 6;
    int lane = threadIdx.x & 63;
    int half = lane >> 5;
    int cl = lane & 31;
    int g = blockIdx.y * 4 + wave;   // cell group 0..15
    int m = blockIdx.x;              // proposal
    int b = m >> 7;
    const float* pr = props + (size_t)m * 5;
    float b0 = pr[0] * SCALEq, b1v = pr[1] * SCALEq;
    float b2v = pr[2] * SCALEq, b3v = pr[3] * SCALEq;
    int x1 = min(max((int)floorf(b0), 0), WFq - 1);
    int y1 = min(max((int)floorf(b1v), 0), HFq - 1);
    int rw = min(max((int)ceilf(b2v) - x1, 1), WFq);
    int rh = min(max((int)ceilf(b3v) - y1, 1), HFq);
    const unsigned short* ftb = ft + (size_t)b * HWq * Cq + cl * 8;
    unsigned short* pm = pooled + (size_t)m * Fq + cl * 8;

    for (int cell = g; cell < PHq * PWq; cell += 16) {
        int ph = cell / 7;
        int pw = cell - ph * 7;
        int hs = y1 + (ph * rh) / PHq;
        int he = min(y1 + ((ph + 1) * rh + PHq - 1) / PHq, HFq);
        int ws = x1 + (pw * rw) / PWq;
        int we = min(x1 + ((pw + 1) * rw + PWq - 1) / PWq, WFq);
        float acc[8];
#pragma unroll
        for (int u = 0; u < 8; ++u) acc[u] = NEGq;
#pragma unroll
        for (int kh = 0; kh < KHq; ++kh) {
            if (hs + kh < he) {                      // wave-uniform
                const unsigned short* rowp = ftb + (size_t)((hs + kh) * WFq) * Cq;
#pragma unroll
                for (int kw2 = 0; kw2 < 3; ++kw2) {
                    int w = ws + kw2 * 2 + half;
                    if (w < we) {                    // half-wave divergent only
                        u16x8 v = *(const u16x8*)(rowp + (size_t)w * Cq);
#pragma unroll
                        for (int u = 0; u < 8; ++u)
                            acc[u] = fmaxf(acc[u], __uint_as_float((unsigned)v[u] << 16));
                    }
                }
            }
        }
#pragma unroll
        for (int u = 0; u < 8; ++u) acc[u] = fmaxf(acc[u], __shfl_xor(acc[u], 32));
        if (half == 0) {
            u16x8 o;
#pragma unroll
            for (int u = 0; u < 8; ++u) o[u] = f2b(acc[u]);
            *(u16x8*)(pm + (size_t)cell * Cq) = o;
        }
    }
}

// K3: GEMM1 with MFMA bf16. BM=64, BN=64, BK=64, double-buffered LDS with
// XOR-swizzled 16B chunks (chunk' = chunk ^ (row&7)) -> conflict-free
// ds_read_b128 / 2-way (free) ds_write. 2-step register lookahead.
// Split-K partials accumulated into h via atomicAdd (h pre-zeroed).
__global__ __launch_bounds__(256) void k_gemm1(const unsigned short* __restrict__ pooled,
                                               const unsigned short* __restrict__ w1p,
                                               float* __restrict__ h) {
    __shared__ __align__(16) unsigned short As[2][64 * BKq];  // 2 x 8 KB
    __shared__ __align__(16) unsigned short Bs[2][64 * BKq];  // 2 x 8 KB
    int m0 = blockIdx.x * 64;
    int j0 = blockIdx.y * 64;
    int kz = blockIdx.z;
    int tid = threadIdx.x;
    int r = tid >> 2, qq = tid & 3;
    // global: uint4 index; row stride Fq/8 uint4; per-step stride 8 uint4
    const uint4* ap = (const uint4*)(pooled + (size_t)(m0 + r) * Fq + (size_t)kz * KCH) + qq;
    const uint4* bp = (const uint4*)(w1p + (size_t)(j0 + r) * Fq + (size_t)kz * KCH) + qq;
    int lane = tid & 63, wv = tid >> 6;
    int q = lane >> 4, mr = lane & 15;
    f32x4 acc0 = {0.f, 0.f, 0.f, 0.f};
    f32x4 acc1 = {0.f, 0.f, 0.f, 0.f};
    f32x4 acc2 = {0.f, 0.f, 0.f, 0.f};
    f32x4 acc3 = {0.f, 0.f, 0.f, 0.f};
    // staging (uint4 units): row r, chunks qq and qq^4, swizzled by r&7
    int st1 = r * 8 + ((qq) ^ (r & 7));
    int st2 = r * 8 + ((qq ^ 4) ^ (r & 7));
    // fragment read offsets (uint4 units): row*8 + ((kk*4+q) ^ (mr&7))
    int sA = (wv * 16 + mr) * 8;
    int c0k0 = (q) ^ (mr & 7);        // kk=0 chunk
    int c0k1 = (q ^ 4) ^ (mr & 7);    // kk=1 chunk  (4+q == 4^q for q<4)

    uint4 a0v = ap[0], a1v = ap[4];
    uint4 b0v = bp[0], b1v = bp[4];
    {   // write step 0 into buf 0
        uint4* aw = (uint4*)As[0];
        uint4* bw = (uint4*)Bs[0];
        aw[st1] = a0v; aw[st2] = a1v;
        bw[st1] = b0v; bw[st2] = b1v;
    }
    a0v = ap[8];  a1v = ap[12];
    b0v = bp[8];  b1v = bp[12];
    for (int s = 0; s < KSTEPS; ++s) {
        __syncthreads();
        int cur = s & 1;
        if (s + 1 < KSTEPS) {
            uint4* aw = (uint4*)As[cur ^ 1];
            uint4* bw = (uint4*)Bs[cur ^ 1];
            aw[st1] = a0v; aw[st2] = a1v;
            bw[st1] = b0v; bw[st2] = b1v;
            if (s + 2 < KSTEPS) {
                a0v = ap[(s + 2) * 8];     a1v = ap[(s + 2) * 8 + 4];
                b0v = bp[(s + 2) * 8];     b1v = bp[(s + 2) * 8 + 4];
            }
        }
        const bf16x8* Ab = (const bf16x8*)As[cur];
        const bf16x8* Bb = (const bf16x8*)Bs[cur];
        bf16x8 a0 = Ab[sA + c0k0];
        bf16x8 a1 = Ab[sA + c0k1];
        acc0 = __builtin_amdgcn_mfma_f32_16x16x32_bf16(a0, Bb[(0  + mr) * 8 + c0k0], acc0, 0, 0, 0);
        acc1 = __builtin_amdgcn_mfma_f32_16x16x32_bf16(a0, Bb[(16 + mr) * 8 + c0k0], acc1, 0, 0, 0);
        acc2 = __builtin_amdgcn_mfma_f32_16x16x32_bf16(a0, Bb[(32 + mr) * 8 + c0k0], acc2, 0, 0, 0);
        acc3 = __builtin_amdgcn_mfma_f32_16x16x32_bf16(a0, Bb[(48 + mr) * 8 + c0k0], acc3, 0, 0, 0);
        acc0 = __builtin_amdgcn_mfma_f32_16x16x32_bf16(a1, Bb[(0  + mr) * 8 + c0k1], acc0, 0, 0, 0);
        acc1 = __builtin_amdgcn_mfma_f32_16x16x32_bf16(a1, Bb[(16 + mr) * 8 + c0k1], acc1, 0, 0, 0);
        acc2 = __builtin_amdgcn_mfma_f32_16x16x32_bf16(a1, Bb[(32 + mr) * 8 + c0k1], acc2, 0, 0, 0);
        acc3 = __builtin_amdgcn_mfma_f32_16x16x32_bf16(a1, Bb[(48 + mr) * 8 + c0k1], acc3, 0, 0, 0);
    }
    int mb = m0 + wv * 16 + q * 4;
    int jj = j0 + mr;
#pragma unroll
    for (int r2 = 0; r2 < 4; ++r2) {
        float* row = h + (size_t)(mb + r2) * HIDq + jj;
        atomicAdd(row + 0,  acc0[r2]);
        atomicAdd(row + 16, acc1[r2]);
        atomicAdd(row + 32, acc2[r2]);
        atomicAdd(row + 48, acc3[r2]);
    }
}

// K4: tail — bias + relu on raw split-K sum, GEMM2 (512 x 5 x 256) + epilogue
__global__ __launch_bounds__(256) void k_tail(const float* __restrict__ h,
                                              const float* __restrict__ b1,
                                              const float* __restrict__ W2,
                                              const float* __restrict__ b2,
                                              const float* __restrict__ props,
                                              float* __restrict__ out) {
    __shared__ float red[OUTq][4];
    int m = blockIdx.x, j = threadIdx.x;
    float hv = fmaxf(h[(size_t)m * HIDq + j] + b1[j], 0.f);
    float p[OUTq];
#pragma unroll
    for (int o = 0; o < OUTq; ++o) p[o] = hv * W2[(size_t)o * HIDq + j];
    int lane = j & 63, wid = j >> 6;
#pragma unroll
    for (int o = 0; o < OUTq; ++o) {
        float v = p[o];
        v += __shfl_xor(v, 1);
        v += __shfl_xor(v, 2);
        v += __shfl_xor(v, 4);
        v += __shfl_xor(v, 8);
        v += __shfl_xor(v, 16);
        v += __shfl_xor(v, 32);
        if (lane == 0) red[o][wid] = v;
    }
    __syncthreads();
    if (j < OUTq) {
        float s = red[j][0] + red[j][1] + red[j][2] + red[j][3] + b2[j];
        float pv = props[(size_t)m * 5 + j];
        float r;
        if (j < 4) r = pv + s;
        else r = 1.f / (1.f + expf(-(pv + s)));
        out[(size_t)m * 5 + j] = r;
    }
}

extern "C" void kernel_launch(void* const* d_in, const int* in_sizes, int n_in,
                              void* d_out, int out_size, void* d_ws, size_t ws_size,
                              hipStream_t stream) {
    const float* feat  = (const float*)d_in[0];   // (4,256,23,30)
    const float* props = (const float*)d_in[1];   // (4,128,5)
    const float* W1    = (const float*)d_in[2];   // (256,12544)
    const float* b1    = (const float*)d_in[3];   // (256,)
    const float* W2    = (const float*)d_in[4];   // (5,256)
    const float* b2    = (const float*)d_in[5];   // (5,)
    float* out = (float*)d_out;

    char* ws = (char*)d_ws;
    unsigned short* ft     = (unsigned short*)(ws);              // 1,413,120 B (bf16)
    unsigned short* w1p    = (unsigned short*)(ws + 1413120);    // 6,422,528 B
    unsigned short* pooled = (unsigned short*)(ws + 7835648);    // 12,845,056 B
    float* h               = (float*)(ws + 20680704);            // 524,288 B -> 21,204,992 total

    k_prep<<<968, 256, 0, stream>>>(feat, ft, W1, w1p, h);
    k_pool<<<dim3(Mq, 4), 256, 0, stream>>>(ft, props, pooled);
    k_gemm1<<<dim3(8, 4, SPLITK), 256, 0, stream>>>(pooled, w1p, h);
    k_tail<<<Mq, 256, 0, stream>>>(h, b1, W2, b2, props, out);
}

// Round 6
// 109.507 us; speedup vs baseline: 1.1988x; 1.0573x over previous
//
#include <hip/hip_runtime.h>
#include <math.h>

#define Bq 4
#define Nq 128
#define Cq 256
#define HFq 23
#define WFq 30
#define PHq 7
#define PWq 7
#define HIDq 256
#define OUTq 5
#define Fq (Cq*PHq*PWq)      // 12544
#define Mq (Bq*Nq)           // 512
#define HWq (HFq*WFq)        // 690
#define SCALEq (1.0f/32.0f)
#define NEGq (-1e30f)
#define KHq 5                // HF//PH + 2
#define KWq 6                // WF//PW + 2
#define SPLITK 14
#define KCH (Fq/SPLITK)      // 896
#define BKq 64
#define KSTEPS (KCH/BKq)     // 14

typedef float f32x4 __attribute__((ext_vector_type(4)));
typedef __bf16 bf16x8 __attribute__((ext_vector_type(8)));
typedef unsigned short u16x8 __attribute__((ext_vector_type(8)));

__device__ __forceinline__ unsigned short f2b(float f) {
    unsigned int u = __float_as_uint(f);
    unsigned int r = (u + 0x7FFFu + ((u >> 16) & 1u)) >> 16;
    return (unsigned short)r;
}

// K1: fused prep. blockIdx.x ranges:
//   [0,704)   : transpose features (B,C,HF,WF) f32 -> (B, HF*WF, C) bf16
//   [704,960) : W1 f32 (HID, c*49+cell) -> bf16 permuted (HID, cell*256+c)
//   [960,968) : zero h (atomicAdd target for split-K GEMM1)
__global__ __launch_bounds__(256) void k_prep(const float* __restrict__ feat,
                                              unsigned short* __restrict__ ft,
                                              const float* __restrict__ W1,
                                              unsigned short* __restrict__ w1p,
                                              float* __restrict__ h) {
    __shared__ __align__(16) unsigned short smem[Fq];   // 25088 B overlay
    int bid = blockIdx.x;
    int tid = threadIdx.x;
    if (bid < 704) {
        // --- transpose tile, f32 -> bf16 ---
        float (*t)[33] = (float (*)[33])smem;           // 32*33*4 = 4224 B
        int bb  = bid / 176;
        int rem = bid % 176;
        int x0 = (rem % 22) * 32;      // HW dim
        int c0 = (rem / 22) * 32;      // C dim
        int tx = tid & 31, ty = tid >> 5;
        const float* src = feat + (size_t)bb * Cq * HWq;
        unsigned short* dst = ft + (size_t)bb * HWq * Cq;
#pragma unroll
        for (int i = 0; i < 4; ++i) {
            int c = c0 + ty + i * 8;
            int x = x0 + tx;
            if (x < HWq) t[ty + i * 8][tx] = src[(size_t)c * HWq + x];  // t[c_loc][x_loc]
        }
        __syncthreads();
        int u = tid & 15, xl = tid >> 4;
#pragma unroll
        for (int i = 0; i < 2; ++i) {
            int xloc = xl + i * 16;
            int x = x0 + xloc;
            if (x < HWq) {
                ushort2 o;
                o.x = f2b(t[u * 2][xloc]);
                o.y = f2b(t[u * 2 + 1][xloc]);
                *(ushort2*)(dst + (size_t)x * Cq + c0 + u * 2) = o;
            }
        }
    } else if (bid < 960) {
        // --- W1 permute + bf16 convert ---
        int j = bid - 704;
        const float4* src = (const float4*)(W1 + (size_t)j * Fq);
        for (int i = tid; i < Fq / 4; i += 256) {
            float4 v = src[i];
            ushort4 o;
            o.x = f2b(v.x); o.y = f2b(v.y); o.z = f2b(v.z); o.w = f2b(v.w);
            ((ushort4*)smem)[i] = o;
        }
        __syncthreads();
        uint4* dst = (uint4*)(w1p + (size_t)j * Fq);
        for (int i = tid; i < Fq / 8; i += 256) {
            int base = i * 8;
            int cell = base >> 8;       // 8 consecutive c share one cell
            int c0v = base & 255;
            unsigned short tmp[8];
#pragma unroll
            for (int u2 = 0; u2 < 8; ++u2) tmp[u2] = smem[(c0v + u2) * 49 + cell];
            dst[i] = *(const uint4*)tmp;
        }
    } else {
        // --- zero h: 512 KB, 8 blocks x 256 threads x 16 float4 ---
        f32x4* h4 = (f32x4*)h;
        int base = (bid - 960) * 4096;
        f32x4 z = {0.f, 0.f, 0.f, 0.f};
#pragma unroll
        for (int u2 = 0; u2 < 16; ++u2) h4[base + u2 * 256 + tid] = z;
    }
}

// K2: ROI max pool over bf16 ft. ONE CELL PER WAVE: grid (Mq,13), wave g =
// blockIdx.y*4+wave handles cell g (g<49). ~25k waves -> max latency hiding.
// Lane split: cl = lane&31 -> 8 channels; half = lane>>5 -> w-positions.
// Combine via shfl_xor(32).
__global__ __launch_bounds__(256) void k_pool(const unsigned short* __restrict__ ft,
                                              const float* __restrict__ props,
                                              unsigned short* __restrict__ pooled) {
    int wave = threadIdx.x >> 6;
    int lane = threadIdx.x & 63;
    int half = lane >> 5;
    int cl = lane & 31;
    int cell = blockIdx.y * 4 + wave;   // 0..51
    if (cell >= PHq * PWq) return;
    int m = blockIdx.x;              // proposal
    int b = m >> 7;
    const float* pr = props + (size_t)m * 5;
    float b0 = pr[0] * SCALEq, b1v = pr[1] * SCALEq;
    float b2v = pr[2] * SCALEq, b3v = pr[3] * SCALEq;
    int x1 = min(max((int)floorf(b0), 0), WFq - 1);
    int y1 = min(max((int)floorf(b1v), 0), HFq - 1);
    int rw = min(max((int)ceilf(b2v) - x1, 1), WFq);
    int rh = min(max((int)ceilf(b3v) - y1, 1), HFq);
    const unsigned short* ftb = ft + (size_t)b * HWq * Cq + cl * 8;
    unsigned short* pm = pooled + (size_t)m * Fq + cl * 8;

    int ph = cell / 7;
    int pw = cell - ph * 7;
    int hs = y1 + (ph * rh) / PHq;
    int he = min(y1 + ((ph + 1) * rh + PHq - 1) / PHq, HFq);
    int ws = x1 + (pw * rw) / PWq;
    int we = min(x1 + ((pw + 1) * rw + PWq - 1) / PWq, WFq);
    float acc[8];
#pragma unroll
    for (int u = 0; u < 8; ++u) acc[u] = NEGq;
#pragma unroll
    for (int kh = 0; kh < KHq; ++kh) {
        if (hs + kh < he) {                      // wave-uniform
            const unsigned short* rowp = ftb + (size_t)((hs + kh) * WFq) * Cq;
#pragma unroll
            for (int kw2 = 0; kw2 < 3; ++kw2) {
                int w = ws + kw2 * 2 + half;
                if (w < we) {                    // half-wave divergent only
                    u16x8 v = *(const u16x8*)(rowp + (size_t)w * Cq);
#pragma unroll
                    for (int u = 0; u < 8; ++u)
                        acc[u] = fmaxf(acc[u], __uint_as_float((unsigned)v[u] << 16));
                }
            }
        }
    }
#pragma unroll
    for (int u = 0; u < 8; ++u) acc[u] = fmaxf(acc[u], __shfl_xor(acc[u], 32));
    if (half == 0) {
        u16x8 o;
#pragma unroll
        for (int u = 0; u < 8; ++u) o[u] = f2b(acc[u]);
        *(u16x8*)(pm + (size_t)cell * Cq) = o;
    }
}

// K3: GEMM1 with MFMA bf16. BM=64, BN=64, BK=64, double-buffered LDS with
// XOR-swizzled 16B chunks (chunk' = chunk ^ (row&7)) -> conflict-free
// ds_read_b128 / 2-way (free) ds_write. 2-step register lookahead.
// Split-K partials accumulated into h via atomicAdd (h pre-zeroed).
__global__ __launch_bounds__(256) void k_gemm1(const unsigned short* __restrict__ pooled,
                                               const unsigned short* __restrict__ w1p,
                                               float* __restrict__ h) {
    __shared__ __align__(16) unsigned short As[2][64 * BKq];  // 2 x 8 KB
    __shared__ __align__(16) unsigned short Bs[2][64 * BKq];  // 2 x 8 KB
    int m0 = blockIdx.x * 64;
    int j0 = blockIdx.y * 64;
    int kz = blockIdx.z;
    int tid = threadIdx.x;
    int r = tid >> 2, qq = tid & 3;
    // global: uint4 index; row stride Fq/8 uint4; per-step stride 8 uint4
    const uint4* ap = (const uint4*)(pooled + (size_t)(m0 + r) * Fq + (size_t)kz * KCH) + qq;
    const uint4* bp = (const uint4*)(w1p + (size_t)(j0 + r) * Fq + (size_t)kz * KCH) + qq;
    int lane = tid & 63, wv = tid >> 6;
    int q = lane >> 4, mr = lane & 15;
    f32x4 acc0 = {0.f, 0.f, 0.f, 0.f};
    f32x4 acc1 = {0.f, 0.f, 0.f, 0.f};
    f32x4 acc2 = {0.f, 0.f, 0.f, 0.f};
    f32x4 acc3 = {0.f, 0.f, 0.f, 0.f};
    // staging (uint4 units): row r, chunks qq and qq^4, swizzled by r&7
    int st1 = r * 8 + ((qq) ^ (r & 7));
    int st2 = r * 8 + ((qq ^ 4) ^ (r & 7));
    // fragment read offsets (uint4 units): row*8 + ((kk*4+q) ^ (mr&7))
    int sA = (wv * 16 + mr) * 8;
    int c0k0 = (q) ^ (mr & 7);        // kk=0 chunk
    int c0k1 = (q ^ 4) ^ (mr & 7);    // kk=1 chunk  (4+q == 4^q for q<4)

    uint4 a0v = ap[0], a1v = ap[4];
    uint4 b0v = bp[0], b1v = bp[4];
    {   // write step 0 into buf 0
        uint4* aw = (uint4*)As[0];
        uint4* bw = (uint4*)Bs[0];
        aw[st1] = a0v; aw[st2] = a1v;
        bw[st1] = b0v; bw[st2] = b1v;
    }
    a0v = ap[8];  a1v = ap[12];
    b0v = bp[8];  b1v = bp[12];
    for (int s = 0; s < KSTEPS; ++s) {
        __syncthreads();
        int cur = s & 1;
        if (s + 1 < KSTEPS) {
            uint4* aw = (uint4*)As[cur ^ 1];
            uint4* bw = (uint4*)Bs[cur ^ 1];
            aw[st1] = a0v; aw[st2] = a1v;
            bw[st1] = b0v; bw[st2] = b1v;
            if (s + 2 < KSTEPS) {
                a0v = ap[(s + 2) * 8];     a1v = ap[(s + 2) * 8 + 4];
                b0v = bp[(s + 2) * 8];     b1v = bp[(s + 2) * 8 + 4];
            }
        }
        const bf16x8* Ab = (const bf16x8*)As[cur];
        const bf16x8* Bb = (const bf16x8*)Bs[cur];
        bf16x8 a0 = Ab[sA + c0k0];
        bf16x8 a1 = Ab[sA + c0k1];
        acc0 = __builtin_amdgcn_mfma_f32_16x16x32_bf16(a0, Bb[(0  + mr) * 8 + c0k0], acc0, 0, 0, 0);
        acc1 = __builtin_amdgcn_mfma_f32_16x16x32_bf16(a0, Bb[(16 + mr) * 8 + c0k0], acc1, 0, 0, 0);
        acc2 = __builtin_amdgcn_mfma_f32_16x16x32_bf16(a0, Bb[(32 + mr) * 8 + c0k0], acc2, 0, 0, 0);
        acc3 = __builtin_amdgcn_mfma_f32_16x16x32_bf16(a0, Bb[(48 + mr) * 8 + c0k0], acc3, 0, 0, 0);
        acc0 = __builtin_amdgcn_mfma_f32_16x16x32_bf16(a1, Bb[(0  + mr) * 8 + c0k1], acc0, 0, 0, 0);
        acc1 = __builtin_amdgcn_mfma_f32_16x16x32_bf16(a1, Bb[(16 + mr) * 8 + c0k1], acc1, 0, 0, 0);
        acc2 = __builtin_amdgcn_mfma_f32_16x16x32_bf16(a1, Bb[(32 + mr) * 8 + c0k1], acc2, 0, 0, 0);
        acc3 = __builtin_amdgcn_mfma_f32_16x16x32_bf16(a1, Bb[(48 + mr) * 8 + c0k1], acc3, 0, 0, 0);
    }
    int mb = m0 + wv * 16 + q * 4;
    int jj = j0 + mr;
#pragma unroll
    for (int r2 = 0; r2 < 4; ++r2) {
        float* row = h + (size_t)(mb + r2) * HIDq + jj;
        atomicAdd(row + 0,  acc0[r2]);
        atomicAdd(row + 16, acc1[r2]);
        atomicAdd(row + 32, acc2[r2]);
        atomicAdd(row + 48, acc3[r2]);
    }
}

// K4: tail — bias + relu on raw split-K sum, GEMM2 (512 x 5 x 256) + epilogue
__global__ __launch_bounds__(256) void k_tail(const float* __restrict__ h,
                                              const float* __restrict__ b1,
                                              const float* __restrict__ W2,
                                              const float* __restrict__ b2,
                                              const float* __restrict__ props,
                                              float* __restrict__ out) {
    __shared__ float red[OUTq][4];
    int m = blockIdx.x, j = threadIdx.x;
    float hv = fmaxf(h[(size_t)m * HIDq + j] + b1[j], 0.f);
    float p[OUTq];
#pragma unroll
    for (int o = 0; o < OUTq; ++o) p[o] = hv * W2[(size_t)o * HIDq + j];
    int lane = j & 63, wid = j >> 6;
#pragma unroll
    for (int o = 0; o < OUTq; ++o) {
        float v = p[o];
        v += __shfl_xor(v, 1);
        v += __shfl_xor(v, 2);
        v += __shfl_xor(v, 4);
        v += __shfl_xor(v, 8);
        v += __shfl_xor(v, 16);
        v += __shfl_xor(v, 32);
        if (lane == 0) red[o][wid] = v;
    }
    __syncthreads();
    if (j < OUTq) {
        float s = red[j][0] + red[j][1] + red[j][2] + red[j][3] + b2[j];
        float pv = props[(size_t)m * 5 + j];
        float r;
        if (j < 4) r = pv + s;
        else r = 1.f / (1.f + expf(-(pv + s)));
        out[(size_t)m * 5 + j] = r;
    }
}

extern "C" void kernel_launch(void* const* d_in, const int* in_sizes, int n_in,
                              void* d_out, int out_size, void* d_ws, size_t ws_size,
                              hipStream_t stream) {
    const float* feat  = (const float*)d_in[0];   // (4,256,23,30)
    const float* props = (const float*)d_in[1];   // (4,128,5)
    const float* W1    = (const float*)d_in[2];   // (256,12544)
    const float* b1    = (const float*)d_in[3];   // (256,)
    const float* W2    = (const float*)d_in[4];   // (5,256)
    const float* b2    = (const float*)d_in[5];   // (5,)
    float* out = (float*)d_out;

    char* ws = (char*)d_ws;
    unsigned short* ft     = (unsigned short*)(ws);              // 1,413,120 B (bf16)
    unsigned short* w1p    = (unsigned short*)(ws + 1413120);    // 6,422,528 B
    unsigned short* pooled = (unsigned short*)(ws + 7835648);    // 12,845,056 B
    float* h               = (float*)(ws + 20680704);            // 524,288 B -> 21,204,992 total

    k_prep<<<968, 256, 0, stream>>>(feat, ft, W1, w1p, h);
    k_pool<<<dim3(Mq, 13), 256, 0, stream>>>(ft, props, pooled);
    k_gemm1<<<dim3(8, 4, SPLITK), 256, 0, stream>>>(pooled, w1p, h);
    k_tail<<<Mq, 256, 0, stream>>>(h, b1, W2, b2, props, out);
}